// Round 3
// baseline (68.209 us; speedup 1.0000x reference)
//
#include <hip/hip_runtime.h>

// RecPolicy: per-row bidirectional GRU (H=2) + obs linear + scalar head.
// x: (B,18) f32 = [obs(4), j(7), jd(7)] ; out: (B,7) f32
//
// R3: scalar math with SGPR-resident raw weights (no VGPR prescale),
//     shared-rcp activation pairs (rcp 84->42/row), per-cell LDS reads of
//     j/jd via ds_read2, launch_bounds(256,6) for occupancy.

__device__ __forceinline__ float fexp2(float x) { return __builtin_amdgcn_exp2f(x); }
__device__ __forceinline__ float frcp(float x)  { return __builtin_amdgcn_rcpf(x); }

#define S1n (-1.4426950408889634f)   // -log2(e): sigmoid(g) = 1/(1+exp2(S1n*g))
#define S2p ( 2.8853900817779268f)   // 2*log2(e): tanh(a) = 1 - 2/(1+exp2(S2p*a))

// sigmoid of g0,g1 with one shared rcp
__device__ __forceinline__ void sigmoid2(float g0, float g1, float& r0, float& r1) {
    float d0 = 1.0f + fexp2(S1n * g0);
    float d1 = 1.0f + fexp2(S1n * g1);
    float inv = frcp(d0 * d1);
    r0 = inv * d1;
    r1 = inv * d0;
}
// tanh of a0,a1 with one shared rcp
__device__ __forceinline__ void tanh2(float a0, float a1, float& n0, float& n1) {
    float d0 = 1.0f + fexp2(S2p * a0);
    float d1 = 1.0f + fexp2(S2p * a1);
    float m = -2.0f * frcp(d0 * d1);
    n0 = fmaf(m, d1, 1.0f);
    n1 = fmaf(m, d0, 1.0f);
}

// One GRU cell, H=2. wi/wh (6,2) row-major [r0,r1,z0,z1,n0,n1], b* (6,).
__device__ __forceinline__ void gru_cell(
    const float* __restrict__ wi, const float* __restrict__ wh,
    const float* __restrict__ bi, const float* __restrict__ bh,
    float x0, float x1, float& h0, float& h1)
{
    float g0 = (bi[0] + bh[0]) + wi[0]*x0 + wi[1]*x1 + wh[0]*h0 + wh[1]*h1;
    float g1 = (bi[1] + bh[1]) + wi[2]*x0 + wi[3]*x1 + wh[2]*h0 + wh[3]*h1;
    float g2 = (bi[2] + bh[2]) + wi[4]*x0 + wi[5]*x1 + wh[4]*h0 + wh[5]*h1;
    float g3 = (bi[3] + bh[3]) + wi[6]*x0 + wi[7]*x1 + wh[6]*h0 + wh[7]*h1;
    float r0, r1, z0, z1;
    sigmoid2(g0, g1, r0, r1);
    sigmoid2(g2, g3, z0, z1);
    float in0 = bi[4] + wi[8]*x0  + wi[9]*x1;
    float in1 = bi[5] + wi[10]*x0 + wi[11]*x1;
    float hn0 = bh[4] + wh[8]*h0  + wh[9]*h1;
    float hn1 = bh[5] + wh[10]*h0 + wh[11]*h1;
    float n0, n1;
    tanh2(in0 + r0 * hn0, in1 + r1 * hn1, n0, n1);
    h0 = n0 + z0 * (h0 - n0);   // (1-z)*n + z*h
    h1 = n1 + z1 * (h1 - n1);
}

__global__ __launch_bounds__(256, 6) void recpolicy_kernel(
    const float* __restrict__ x,
    const float* __restrict__ w_ih_up, const float* __restrict__ w_hh_up,
    const float* __restrict__ b_ih_up, const float* __restrict__ b_hh_up,
    const float* __restrict__ w_obs,   const float* __restrict__ b_obs,
    const float* __restrict__ w_ih_dn, const float* __restrict__ w_hh_dn,
    const float* __restrict__ b_ih_dn, const float* __restrict__ b_hh_dn,
    const float* __restrict__ w_out,   const float* __restrict__ b_out,
    float* __restrict__ out, int n)
{
    __shared__ float lds[4608];               // 256 rows x 18 f32 = 18 KiB
    const int tid  = threadIdx.x;
    const int row0 = blockIdx.x * 256;
    const int rows = min(256, n - row0);

    // ---- stage input block into LDS, coalesced float4 ----
    if (rows == 256) {
        const float4* src = reinterpret_cast<const float4*>(x + (size_t)row0 * 18);
        float4* dst = reinterpret_cast<float4*>(lds);
        #pragma unroll
        for (int i = 0; i < 5; ++i) {
            int idx = tid + i * 256;
            if (idx < 1152) dst[idx] = src[idx];
        }
    } else {
        for (int idx = tid; idx < rows * 18; idx += 256)
            lds[idx] = x[(size_t)row0 * 18 + idx];
    }
    __syncthreads();

    const float* myrow = lds + tid * 18;

    // ---- up chain: i = 6..0, input (j[i], jd[i]) = row[4+i], row[11+i] ----
    // per-cell LDS reads: constant-offset pairs merge into ds_read2_b32
    float h0 = 0.0f, h1 = 0.0f;
    float hu0[7], hu1[7];
    #pragma unroll
    for (int k = 0; k < 7; ++k) {
        const int i = 6 - k;
        float xj  = myrow[4 + i];
        float xjd = myrow[11 + i];
        gru_cell(w_ih_up, w_hh_up, b_ih_up, b_hh_up, xj, xjd, h0, h1);
        hu0[k] = h0;
        hu1[k] = h1;
    }

    // ---- obs linear: [obs(4), h(2)] @ w_obs.T + b_obs  (w_obs is (2,6)) ----
    {
        float o0 = myrow[0], o1 = myrow[1], o2 = myrow[2], o3 = myrow[3];
        float t0 = b_obs[0] + w_obs[0]*o0 + w_obs[1]*o1 + w_obs[2]*o2 + w_obs[3]*o3
                 + w_obs[4]*h0 + w_obs[5]*h1;
        float t1 = b_obs[1] + w_obs[6]*o0 + w_obs[7]*o1 + w_obs[8]*o2 + w_obs[9]*o3
                 + w_obs[10]*h0 + w_obs[11]*h1;
        h0 = t0;
        h1 = t1;
    }
    __syncthreads();   // all input reads done before lds is reused for output

    // ---- down chain + head, acts staged into LDS ----
    const float wo0 = w_out[0], wo1 = w_out[1], bo = b_out[0];
    #pragma unroll
    for (int k = 0; k < 7; ++k) {
        gru_cell(w_ih_dn, w_hh_dn, b_ih_dn, b_hh_dn, hu0[k], hu1[k], h0, h1);
        lds[tid * 7 + k] = fmaf(wo0, h0, fmaf(wo1, h1, bo));
    }
    __syncthreads();

    // ---- coalesced float4 store of the block's 256x7 outputs ----
    if (rows == 256) {
        float4* dst = reinterpret_cast<float4*>(out + (size_t)row0 * 7);
        const float4* src = reinterpret_cast<const float4*>(lds);
        #pragma unroll
        for (int i = 0; i < 2; ++i) {
            int idx = tid + i * 256;
            if (idx < 448) dst[idx] = src[idx];
        }
    } else {
        for (int idx = tid; idx < rows * 7; idx += 256)
            out[(size_t)row0 * 7 + idx] = lds[idx];
    }
}

extern "C" void kernel_launch(void* const* d_in, const int* in_sizes, int n_in,
                              void* d_out, int out_size, void* d_ws, size_t ws_size,
                              hipStream_t stream) {
    const float* x       = (const float*)d_in[0];
    const float* w_ih_up = (const float*)d_in[1];
    const float* w_hh_up = (const float*)d_in[2];
    const float* b_ih_up = (const float*)d_in[3];
    const float* b_hh_up = (const float*)d_in[4];
    const float* w_obs   = (const float*)d_in[5];
    const float* b_obs   = (const float*)d_in[6];
    const float* w_ih_dn = (const float*)d_in[7];
    const float* w_hh_dn = (const float*)d_in[8];
    const float* b_ih_dn = (const float*)d_in[9];
    const float* b_hh_dn = (const float*)d_in[10];
    const float* w_out   = (const float*)d_in[11];
    const float* b_out   = (const float*)d_in[12];
    float* out = (float*)d_out;

    const int n = in_sizes[0] / 18;
    const int block = 256;
    const int grid = (n + block - 1) / block;
    recpolicy_kernel<<<grid, block, 0, stream>>>(
        x, w_ih_up, w_hh_up, b_ih_up, b_hh_up, w_obs, b_obs,
        w_ih_dn, w_hh_dn, b_ih_dn, b_hh_dn, w_out, b_out, out, n);
}

// Round 5
// 54.753 us; speedup vs baseline: 1.2458x; 1.2458x over previous
//
#include <hip/hip_runtime.h>

// RecPolicy: per-row bidirectional GRU (H=2) + obs linear + scalar head.
// x: (B,18) f32 = [obs(4), j(7), jd(7)] ; out: (B,7) f32
//
// R5 = R4 with the dn-cell offset bug fixed: prep writes cells at float
// offsets 0 and 64; sizeof(Cell)=32 floats, so main must read W+0 and W+64
// (R4's cells[1] read W+32 = uninitialized -> absmax 3.9e-2).

using v2f = __attribute__((ext_vector_type(2))) float;

__device__ __forceinline__ float fexp2(float x) { return __builtin_amdgcn_exp2f(x); }
__device__ __forceinline__ float frcp(float x)  { return __builtin_amdgcn_rcpf(x); }

struct Cell {
    v2f wr0, wr1, ur0, ur1, br;   // r gates, prescaled by -log2(e)
    v2f wz0, wz1, uz0, uz1, bz;   // z gates, prescaled by -log2(e)
    v2f wn0, wn1, bni;            // n input part, prescaled by 2*log2(e)
    v2f un0, un1, bnh;            // n hidden part, prescaled by 2*log2(e)
};

// ---- setup kernel: prescale weights once into d_ws ----
// ws layout (floats): [0..31] up Cell, [64..95] dn Cell,
//                     [128..139] w_obs, [140..141] b_obs,
//                     [142..143] w_out, [144] b_out
__global__ void prep_kernel(
    const float* __restrict__ w_ih_up, const float* __restrict__ w_hh_up,
    const float* __restrict__ b_ih_up, const float* __restrict__ b_hh_up,
    const float* __restrict__ w_obs,   const float* __restrict__ b_obs,
    const float* __restrict__ w_ih_dn, const float* __restrict__ w_hh_dn,
    const float* __restrict__ b_ih_dn, const float* __restrict__ b_hh_dn,
    const float* __restrict__ w_out,   const float* __restrict__ b_out,
    float* __restrict__ ws)
{
    if (threadIdx.x != 0 || blockIdx.x != 0) return;
    const float s1 = -1.4426950408889634f;  // -log2(e)
    const float s2 =  2.8853900817779268f;  // 2*log2(e)
    #pragma unroll
    for (int c = 0; c < 2; ++c) {
        const float* wi = c ? w_ih_dn : w_ih_up;
        const float* wh = c ? w_hh_dn : w_hh_up;
        const float* bi = c ? b_ih_dn : b_ih_up;
        const float* bh = c ? b_hh_dn : b_hh_up;
        float* o = ws + c * 64;
        // matches Cell field order: wr0,wr1,ur0,ur1,br, wz0,wz1,uz0,uz1,bz,
        //                           wn0,wn1,bni, un0,un1,bnh
        o[0] = s1*wi[0]; o[1] = s1*wi[2];  o[2] = s1*wi[1]; o[3] = s1*wi[3];
        o[4] = s1*wh[0]; o[5] = s1*wh[2];  o[6] = s1*wh[1]; o[7] = s1*wh[3];
        o[8] = s1*(bi[0]+bh[0]); o[9] = s1*(bi[1]+bh[1]);
        o[10] = s1*wi[4]; o[11] = s1*wi[6]; o[12] = s1*wi[5]; o[13] = s1*wi[7];
        o[14] = s1*wh[4]; o[15] = s1*wh[6]; o[16] = s1*wh[5]; o[17] = s1*wh[7];
        o[18] = s1*(bi[2]+bh[2]); o[19] = s1*(bi[3]+bh[3]);
        o[20] = s2*wi[8]; o[21] = s2*wi[10]; o[22] = s2*wi[9]; o[23] = s2*wi[11];
        o[24] = s2*bi[4]; o[25] = s2*bi[5];
        o[26] = s2*wh[8]; o[27] = s2*wh[10]; o[28] = s2*wh[9]; o[29] = s2*wh[11];
        o[30] = s2*bh[4]; o[31] = s2*bh[5];
    }
    #pragma unroll
    for (int i = 0; i < 12; ++i) ws[128 + i] = w_obs[i];
    ws[140] = b_obs[0]; ws[141] = b_obs[1];
    ws[142] = w_out[0]; ws[143] = w_out[1];
    ws[144] = b_out[0];
}

__device__ __forceinline__ void gru(const Cell& c, float x0, float x1, v2f& h) {
    v2f gr = c.br + c.wr0 * x0 + c.wr1 * x1 + c.ur0 * h.x + c.ur1 * h.y;
    v2f gz = c.bz + c.wz0 * x0 + c.wz1 * x1 + c.uz0 * h.x + c.uz1 * h.y;
    v2f r  = (v2f){ frcp(1.0f + fexp2(gr.x)), frcp(1.0f + fexp2(gr.y)) };
    v2f z  = (v2f){ frcp(1.0f + fexp2(gz.x)), frcp(1.0f + fexp2(gz.y)) };
    v2f in = c.bni + c.wn0 * x0 + c.wn1 * x1;
    v2f hn = c.bnh + c.un0 * h.x + c.un1 * h.y;
    v2f a  = in + r * hn;
    v2f n  = (v2f){ 1.0f - 2.0f * frcp(1.0f + fexp2(a.x)),
                    1.0f - 2.0f * frcp(1.0f + fexp2(a.y)) };
    h = n + z * (h - n);   // (1-z)*n + z*h
}

__global__ __launch_bounds__(256) void recpolicy_kernel(
    const float* __restrict__ x, const float* __restrict__ W,
    float* __restrict__ out, int n)
{
    __shared__ float lds[4608];               // 256 rows x 18 f32 = 18 KiB
    const int tid  = threadIdx.x;
    const int row0 = blockIdx.x * 256;
    const int rows = min(256, n - row0);

    // ---- stage input block into LDS, coalesced float4 ----
    if (rows == 256) {
        const float4* src = reinterpret_cast<const float4*>(x + (size_t)row0 * 18);
        float4* dst = reinterpret_cast<float4*>(lds);
        #pragma unroll
        for (int i = 0; i < 5; ++i) {
            int idx = tid + i * 256;
            if (idx < 1152) dst[idx] = src[idx];
        }
    } else {
        for (int idx = tid; idx < rows * 18; idx += 256)
            lds[idx] = x[(size_t)row0 * 18 + idx];
    }

    // ---- wave-uniform prescaled weights (constant indices -> s_load) ----
    const Cell up = *reinterpret_cast<const Cell*>(W);
    const Cell dn = *reinterpret_cast<const Cell*>(W + 64);

    __syncthreads();

    // ---- each thread pulls its row (b64 LDS reads) ----
    float xv[18];
    {
        const float2* r2 = reinterpret_cast<const float2*>(lds + tid * 18);
        #pragma unroll
        for (int i = 0; i < 9; ++i) { float2 v = r2[i]; xv[2*i] = v.x; xv[2*i+1] = v.y; }
    }
    __syncthreads();   // all input reads done before lds is reused for output

    // ---- up chain: i = 6..0, input (j[i], jd[i]) = (xv[4+i], xv[11+i]) ----
    v2f h = (v2f){0.0f, 0.0f};
    v2f hu[7];
    #pragma unroll
    for (int k = 0; k < 7; ++k) {
        const int i = 6 - k;
        gru(up, xv[4 + i], xv[11 + i], h);
        hu[k] = h;
    }

    // ---- obs linear: [obs(4), h(2)] @ w_obs.T + b_obs  (w_obs is (2,6)) ----
    {
        v2f t = (v2f){W[140], W[141]};
        #pragma unroll
        for (int c = 0; c < 4; ++c)
            t += (v2f){W[128 + c], W[134 + c]} * xv[c];
        t += (v2f){W[132], W[138]} * h.x;
        t += (v2f){W[133], W[139]} * h.y;
        h = t;
    }

    // ---- down chain + head, acts staged into LDS ----
    const float wo0 = W[142], wo1 = W[143], bo = W[144];
    #pragma unroll
    for (int k = 0; k < 7; ++k) {
        gru(dn, hu[k].x, hu[k].y, h);
        lds[tid * 7 + k] = fmaf(wo0, h.x, fmaf(wo1, h.y, bo));
    }
    __syncthreads();

    // ---- coalesced float4 store of the block's 256x7 outputs ----
    if (rows == 256) {
        float4* dst = reinterpret_cast<float4*>(out + (size_t)row0 * 7);
        const float4* src = reinterpret_cast<const float4*>(lds);
        #pragma unroll
        for (int i = 0; i < 2; ++i) {
            int idx = tid + i * 256;
            if (idx < 448) dst[idx] = src[idx];
        }
    } else {
        for (int idx = tid; idx < rows * 7; idx += 256)
            out[(size_t)row0 * 7 + idx] = lds[idx];
    }
}

extern "C" void kernel_launch(void* const* d_in, const int* in_sizes, int n_in,
                              void* d_out, int out_size, void* d_ws, size_t ws_size,
                              hipStream_t stream) {
    const float* x       = (const float*)d_in[0];
    const float* w_ih_up = (const float*)d_in[1];
    const float* w_hh_up = (const float*)d_in[2];
    const float* b_ih_up = (const float*)d_in[3];
    const float* b_hh_up = (const float*)d_in[4];
    const float* w_obs   = (const float*)d_in[5];
    const float* b_obs   = (const float*)d_in[6];
    const float* w_ih_dn = (const float*)d_in[7];
    const float* w_hh_dn = (const float*)d_in[8];
    const float* b_ih_dn = (const float*)d_in[9];
    const float* b_hh_dn = (const float*)d_in[10];
    const float* w_out   = (const float*)d_in[11];
    const float* b_out   = (const float*)d_in[12];
    float* out = (float*)d_out;
    float* ws  = (float*)d_ws;

    prep_kernel<<<1, 64, 0, stream>>>(
        w_ih_up, w_hh_up, b_ih_up, b_hh_up, w_obs, b_obs,
        w_ih_dn, w_hh_dn, b_ih_dn, b_hh_dn, w_out, b_out, ws);

    const int n = in_sizes[0] / 18;
    const int block = 256;
    const int grid = (n + block - 1) / block;
    recpolicy_kernel<<<grid, block, 0, stream>>>(x, ws, out, n);
}

// Round 6
// 53.109 us; speedup vs baseline: 1.2843x; 1.0310x over previous
//
#include <hip/hip_runtime.h>

// RecPolicy: per-row bidirectional GRU (H=2) + obs linear + scalar head.
// x: (B,18) f32 = [obs(4), j(7), jd(7)] ; out: (B,7) f32
//
// R6 = R5 + 2 rows per thread (2-way ILP to fill latency stalls of the
// serial 14-cell GRU chain). Block = 256 threads covers 512 rows; LDS 36KB
// input stage reused for output stage. Weights prescaled once into d_ws.

using v2f = __attribute__((ext_vector_type(2))) float;

__device__ __forceinline__ float fexp2(float x) { return __builtin_amdgcn_exp2f(x); }
__device__ __forceinline__ float frcp(float x)  { return __builtin_amdgcn_rcpf(x); }

struct Cell {
    v2f wr0, wr1, ur0, ur1, br;   // r gates, prescaled by -log2(e)
    v2f wz0, wz1, uz0, uz1, bz;   // z gates, prescaled by -log2(e)
    v2f wn0, wn1, bni;            // n input part, prescaled by 2*log2(e)
    v2f un0, un1, bnh;            // n hidden part, prescaled by 2*log2(e)
};

// ---- setup kernel: prescale weights once into d_ws ----
// ws layout (floats): [0..31] up Cell, [64..95] dn Cell,
//                     [128..139] w_obs, [140..141] b_obs,
//                     [142..143] w_out, [144] b_out
__global__ void prep_kernel(
    const float* __restrict__ w_ih_up, const float* __restrict__ w_hh_up,
    const float* __restrict__ b_ih_up, const float* __restrict__ b_hh_up,
    const float* __restrict__ w_obs,   const float* __restrict__ b_obs,
    const float* __restrict__ w_ih_dn, const float* __restrict__ w_hh_dn,
    const float* __restrict__ b_ih_dn, const float* __restrict__ b_hh_dn,
    const float* __restrict__ w_out,   const float* __restrict__ b_out,
    float* __restrict__ ws)
{
    if (threadIdx.x != 0 || blockIdx.x != 0) return;
    const float s1 = -1.4426950408889634f;  // -log2(e)
    const float s2 =  2.8853900817779268f;  // 2*log2(e)
    #pragma unroll
    for (int c = 0; c < 2; ++c) {
        const float* wi = c ? w_ih_dn : w_ih_up;
        const float* wh = c ? w_hh_dn : w_hh_up;
        const float* bi = c ? b_ih_dn : b_ih_up;
        const float* bh = c ? b_hh_dn : b_hh_up;
        float* o = ws + c * 64;
        o[0] = s1*wi[0]; o[1] = s1*wi[2];  o[2] = s1*wi[1]; o[3] = s1*wi[3];
        o[4] = s1*wh[0]; o[5] = s1*wh[2];  o[6] = s1*wh[1]; o[7] = s1*wh[3];
        o[8] = s1*(bi[0]+bh[0]); o[9] = s1*(bi[1]+bh[1]);
        o[10] = s1*wi[4]; o[11] = s1*wi[6]; o[12] = s1*wi[5]; o[13] = s1*wi[7];
        o[14] = s1*wh[4]; o[15] = s1*wh[6]; o[16] = s1*wh[5]; o[17] = s1*wh[7];
        o[18] = s1*(bi[2]+bh[2]); o[19] = s1*(bi[3]+bh[3]);
        o[20] = s2*wi[8]; o[21] = s2*wi[10]; o[22] = s2*wi[9]; o[23] = s2*wi[11];
        o[24] = s2*bi[4]; o[25] = s2*bi[5];
        o[26] = s2*wh[8]; o[27] = s2*wh[10]; o[28] = s2*wh[9]; o[29] = s2*wh[11];
        o[30] = s2*bh[4]; o[31] = s2*bh[5];
    }
    #pragma unroll
    for (int i = 0; i < 12; ++i) ws[128 + i] = w_obs[i];
    ws[140] = b_obs[0]; ws[141] = b_obs[1];
    ws[142] = w_out[0]; ws[143] = w_out[1];
    ws[144] = b_out[0];
}

__device__ __forceinline__ void gru(const Cell& c, float x0, float x1, v2f& h) {
    v2f gr = c.br + c.wr0 * x0 + c.wr1 * x1 + c.ur0 * h.x + c.ur1 * h.y;
    v2f gz = c.bz + c.wz0 * x0 + c.wz1 * x1 + c.uz0 * h.x + c.uz1 * h.y;
    v2f r  = (v2f){ frcp(1.0f + fexp2(gr.x)), frcp(1.0f + fexp2(gr.y)) };
    v2f z  = (v2f){ frcp(1.0f + fexp2(gz.x)), frcp(1.0f + fexp2(gz.y)) };
    v2f in = c.bni + c.wn0 * x0 + c.wn1 * x1;
    v2f hn = c.bnh + c.un0 * h.x + c.un1 * h.y;
    v2f a  = in + r * hn;
    v2f n  = (v2f){ 1.0f - 2.0f * frcp(1.0f + fexp2(a.x)),
                    1.0f - 2.0f * frcp(1.0f + fexp2(a.y)) };
    h = n + z * (h - n);   // (1-z)*n + z*h
}

__global__ __launch_bounds__(256) void recpolicy_kernel(
    const float* __restrict__ x, const float* __restrict__ W,
    float* __restrict__ out, int n)
{
    __shared__ float lds[9216];               // 512 rows x 18 f32 = 36 KiB
    const int tid  = threadIdx.x;
    const int row0 = blockIdx.x * 512;
    const int rows = min(512, n - row0);

    // ---- stage input block into LDS, coalesced float4 ----
    if (rows == 512) {
        const float4* src = reinterpret_cast<const float4*>(x + (size_t)row0 * 18);
        float4* dst = reinterpret_cast<float4*>(lds);
        #pragma unroll
        for (int i = 0; i < 9; ++i)
            dst[tid + i * 256] = src[tid + i * 256];
    } else {
        for (int idx = tid; idx < rows * 18; idx += 256)
            lds[idx] = x[(size_t)row0 * 18 + idx];
    }

    // ---- wave-uniform prescaled weights ----
    const Cell up = *reinterpret_cast<const Cell*>(W);
    const Cell dn = *reinterpret_cast<const Cell*>(W + 64);

    __syncthreads();

    const bool has2 = (tid + 256) < rows;
    const float* rowA = lds + tid * 18;
    const float* rowB = lds + (tid + 256) * 18;

    // ---- up chain: i = 6..0, input (j[i], jd[i]) = row[4+i], row[11+i] ----
    v2f hA = (v2f){0.0f, 0.0f}, hB = (v2f){0.0f, 0.0f};
    v2f huA[7], huB[7];
    #pragma unroll
    for (int k = 0; k < 7; ++k) {
        const int i = 6 - k;
        gru(up, rowA[4 + i], rowA[11 + i], hA);
        gru(up, rowB[4 + i], rowB[11 + i], hB);
        huA[k] = hA;
        huB[k] = hB;
    }

    // ---- obs linear: [obs(4), h(2)] @ w_obs.T + b_obs  (w_obs is (2,6)) ----
    {
        v2f tA = (v2f){W[140], W[141]};
        v2f tB = tA;
        #pragma unroll
        for (int c = 0; c < 4; ++c) {
            v2f wc = (v2f){W[128 + c], W[134 + c]};
            tA += wc * rowA[c];
            tB += wc * rowB[c];
        }
        v2f w4 = (v2f){W[132], W[138]};
        v2f w5 = (v2f){W[133], W[139]};
        tA += w4 * hA.x + w5 * hA.y;
        tB += w4 * hB.x + w5 * hB.y;
        hA = tA;
        hB = tB;
    }
    __syncthreads();   // all input reads done before lds is reused for output

    // ---- down chain + head, acts staged into LDS ----
    const float wo0 = W[142], wo1 = W[143], bo = W[144];
    #pragma unroll
    for (int k = 0; k < 7; ++k) {
        gru(dn, huA[k].x, huA[k].y, hA);
        gru(dn, huB[k].x, huB[k].y, hB);
        lds[tid * 7 + k] = fmaf(wo0, hA.x, fmaf(wo1, hA.y, bo));
        lds[(tid + 256) * 7 + k] = fmaf(wo0, hB.x, fmaf(wo1, hB.y, bo));
    }
    __syncthreads();

    // ---- coalesced float4 store of the block's 512x7 outputs ----
    if (rows == 512) {
        float4* dst = reinterpret_cast<float4*>(out + (size_t)row0 * 7);
        const float4* src = reinterpret_cast<const float4*>(lds);
        #pragma unroll
        for (int i = 0; i < 4; ++i) {
            int idx = tid + i * 256;
            if (idx < 896) dst[idx] = src[idx];
        }
    } else {
        for (int idx = tid; idx < rows * 7; idx += 256)
            out[(size_t)row0 * 7 + idx] = lds[idx];
    }
    (void)has2;
}

extern "C" void kernel_launch(void* const* d_in, const int* in_sizes, int n_in,
                              void* d_out, int out_size, void* d_ws, size_t ws_size,
                              hipStream_t stream) {
    const float* x       = (const float*)d_in[0];
    const float* w_ih_up = (const float*)d_in[1];
    const float* w_hh_up = (const float*)d_in[2];
    const float* b_ih_up = (const float*)d_in[3];
    const float* b_hh_up = (const float*)d_in[4];
    const float* w_obs   = (const float*)d_in[5];
    const float* b_obs   = (const float*)d_in[6];
    const float* w_ih_dn = (const float*)d_in[7];
    const float* w_hh_dn = (const float*)d_in[8];
    const float* b_ih_dn = (const float*)d_in[9];
    const float* b_hh_dn = (const float*)d_in[10];
    const float* w_out   = (const float*)d_in[11];
    const float* b_out   = (const float*)d_in[12];
    float* out = (float*)d_out;
    float* ws  = (float*)d_ws;

    prep_kernel<<<1, 64, 0, stream>>>(
        w_ih_up, w_hh_up, b_ih_up, b_hh_up, w_obs, b_obs,
        w_ih_dn, w_hh_dn, b_ih_dn, b_hh_dn, w_out, b_out, ws);

    const int n = in_sizes[0] / 18;
    const int block = 256;
    const int grid = (n + 511) / 512;
    recpolicy_kernel<<<grid, block, 0, stream>>>(x, ws, out, n);
}